// Round 1
// baseline (178.768 us; speedup 1.0000x reference)
//
#include <hip/hip_runtime.h>
#include <math.h>

#define D 128

// ---------------------------------------------------------------------------
// Kernel 1: per-node attention logit  s[n] = dot(W2, tanh(W1 @ N[n]))
//   W1 is [128,128] row-major, h[e] = sum_d W1[e][d] * N[n][d]
// Block = 256 (4 waves). W1 staged in LDS with 129-float row pitch
// (bank = (row + d) % 32 -> 2 lanes/bank = conflict-free).
// Each wave processes 4 nodes at once; lane l owns output rows l and l+64.
// ---------------------------------------------------------------------------
__global__ __launch_bounds__(256, 2) void node_score_kernel(
    const float* __restrict__ Nmat, const float* __restrict__ W1,
    const float* __restrict__ W2, float* __restrict__ s, int nNodes)
{
    __shared__ float W1s[128 * 129];     // 66,048 B, padded rows
    __shared__ float4 Nbuf4[16 * 32];    // 16 nodes x 128 floats, 8 KB
    __shared__ float W2s[128];

    const int t = threadIdx.x;

    // stage W1 (16384 floats, 64 per thread), coalesced reads, padded writes
    for (int k = 0; k < 64; ++k) {
        int idx = t + k * 256;
        int row = idx >> 7, d = idx & 127;
        W1s[row * 129 + d] = W1[idx];
    }
    if (t < 128) W2s[t] = W2[t];
    __syncthreads();

    const int wave = t >> 6, lane = t & 63;
    const float w2a = W2s[lane], w2b = W2s[lane + 64];
    const float* w1a = &W1s[lane * 129];
    const float* w1b = &W1s[(lane + 64) * 129];
    const float4* Nv = (const float4*)Nmat;

    for (int base = blockIdx.x * 16; base < nNodes; base += gridDim.x * 16) {
        // stage 16 node vectors (512 float4, 2 per thread)
        for (int k = 0; k < 2; ++k) {
            int idx = t + k * 256;               // 0..511
            int node = idx >> 5, c = idx & 31;
            int n = base + node;
            if (n < nNodes) Nbuf4[node * 32 + c] = Nv[(size_t)n * 32 + c];
        }
        __syncthreads();

        float acc0[4] = {0.f, 0.f, 0.f, 0.f};
        float acc1[4] = {0.f, 0.f, 0.f, 0.f};
        const float4* nb4 = &Nbuf4[wave * 4 * 32];

        #pragma unroll 4
        for (int c = 0; c < 32; ++c) {
            float4 nv[4];
            nv[0] = nb4[c];
            nv[1] = nb4[32 + c];
            nv[2] = nb4[64 + c];
            nv[3] = nb4[96 + c];
            #pragma unroll
            for (int k = 0; k < 4; ++k) {
                float a0 = w1a[4 * c + k];
                float a1 = w1b[4 * c + k];
                #pragma unroll
                for (int q = 0; q < 4; ++q) {
                    float nvv = ((const float*)&nv[q])[k];
                    acc0[q] = fmaf(a0, nvv, acc0[q]);
                    acc1[q] = fmaf(a1, nvv, acc1[q]);
                }
            }
        }

        // epilogue: s[n] = sum_e W2[e]*tanh(h[e]); reduce across 64 lanes
        #pragma unroll
        for (int q = 0; q < 4; ++q) {
            float v = w2a * tanhf(acc0[q]) + w2b * tanhf(acc1[q]);
            #pragma unroll
            for (int o = 32; o > 0; o >>= 1) v += __shfl_xor(v, o, 64);
            int n = base + wave * 4 + q;
            if (lane == 0 && n < nNodes) s[n] = v;
        }
        __syncthreads();   // before Nbuf overwrite next iteration
    }
}

// ---------------------------------------------------------------------------
// Kernel 2: CSR offsets from sorted dst.  off[v] = first edge with dst >= v,
// off[nNodes] = nEdges.  Every entry written exactly once (no init needed).
// ---------------------------------------------------------------------------
__global__ void build_off_kernel(const int* __restrict__ dst, int* __restrict__ off,
                                 int nEdges, int nNodes)
{
    int i = blockIdx.x * blockDim.x + threadIdx.x;
    if (i >= nEdges) return;
    int d = dst[i];
    int dprev = (i == 0) ? -1 : dst[i - 1];
    for (int v = dprev + 1; v <= d; ++v) off[v] = i;
    if (i == nEdges - 1) {
        for (int v = d + 1; v <= nNodes; ++v) off[v] = nEdges;
    }
}

// ---------------------------------------------------------------------------
// Kernel 3: per-destination segment softmax + weighted neighbor sum.
// One 64-lane wave per destination node; lane l owns output columns 2l, 2l+1.
// Phase 1/2: lane-per-edge max & sum-exp with __shfl_xor reductions.
// Phase 3: serial edge loop; weight/src broadcast via __shfl; coalesced
// float2 row gather of N[src].
// ---------------------------------------------------------------------------
__global__ __launch_bounds__(256) void aggregate_kernel(
    const float* __restrict__ Nmat, const int* __restrict__ src,
    const float* __restrict__ s, const int* __restrict__ off,
    float* __restrict__ out, int nNodes)
{
    const int wave = threadIdx.x >> 6, lane = threadIdx.x & 63;
    const int v = blockIdx.x * 4 + wave;
    if (v >= nNodes) return;

    const int start = off[v], end = off[v + 1];
    const int deg = end - start;

    float2 acc = make_float2(0.f, 0.f);

    if (deg > 0) {
        // ---- phase 1: per-lane edge score, wave max ----
        float e_val = -INFINITY;
        int src_val = 0;
        if (lane < deg) {
            src_val = src[start + lane];
            e_val = s[src_val];
        }
        float m = e_val;
        for (int i = start + 64 + lane; i < end; i += 64)
            m = fmaxf(m, s[src[i]]);
        #pragma unroll
        for (int o = 32; o > 0; o >>= 1) m = fmaxf(m, __shfl_xor(m, o, 64));

        // ---- phase 2: sum of exp ----
        float w_val = (lane < deg) ? expf(e_val - m) : 0.f;
        float z = w_val;
        for (int i = start + 64 + lane; i < end; i += 64)
            z += expf(s[src[i]] - m);
        #pragma unroll
        for (int o = 32; o > 0; o >>= 1) z += __shfl_xor(z, o, 64);
        const float invz = 1.0f / z;

        // ---- phase 3: weighted row accumulation ----
        const float2* N2 = (const float2*)Nmat;
        const int dmain = min(deg, 64);
        for (int j = 0; j < dmain; ++j) {
            float wj = __shfl(w_val, j, 64) * invz;
            int sj = __shfl(src_val, j, 64);
            float2 nv = N2[(size_t)sj * 64 + lane];
            acc.x = fmaf(wj, nv.x, acc.x);
            acc.y = fmaf(wj, nv.y, acc.y);
        }
        // rare fallback: degree > 64
        for (int i = start + 64; i < end; ++i) {
            int sj = src[i];                       // uniform across lanes
            float wj = expf(s[sj] - m) * invz;
            float2 nv = N2[(size_t)sj * 64 + lane];
            acc.x = fmaf(wj, nv.x, acc.x);
            acc.y = fmaf(wj, nv.y, acc.y);
        }
    }
    ((float2*)out)[(size_t)v * 64 + lane] = acc;   // zeros for deg==0 nodes
}

// ---------------------------------------------------------------------------
extern "C" void kernel_launch(void* const* d_in, const int* in_sizes, int n_in,
                              void* d_out, int out_size, void* d_ws, size_t ws_size,
                              hipStream_t stream)
{
    const float* Nmat = (const float*)d_in[0];
    const int* src    = (const int*)d_in[1];
    const int* dst    = (const int*)d_in[2];
    const float* W1   = (const float*)d_in[3];
    const float* W2   = (const float*)d_in[4];
    float* out        = (float*)d_out;

    const int nNodes = in_sizes[0] / D;
    const int nEdges = in_sizes[1];

    // workspace layout: s [nNodes floats] | off [nNodes+1 ints]
    float* s  = (float*)d_ws;
    int* off  = (int*)((char*)d_ws + ((((size_t)nNodes * 4) + 255) & ~(size_t)255));

    node_score_kernel<<<512, 256, 0, stream>>>(Nmat, W1, W2, s, nNodes);
    build_off_kernel<<<(nEdges + 255) / 256, 256, 0, stream>>>(dst, off, nEdges, nNodes);
    aggregate_kernel<<<(nNodes + 3) / 4, 256, 0, stream>>>(Nmat, src, s, off, out, nNodes);
}